// Round 5
// baseline (641.649 us; speedup 1.0000x reference)
//
#include <hip/hip_runtime.h>
#include <math.h>

#define N_NODES 50000
#define DIM 64
#define NE 800000
#define NSCAN_BLOCKS ((N_NODES + 255) / 256)   // 196

static __device__ __forceinline__ float bf2f(unsigned short u) {
    return __uint_as_float(((unsigned int)u) << 16);
}
static __device__ __forceinline__ unsigned short f2bf(float f) {
    unsigned int u = __float_as_uint(f);
    u += 0x7fffu + ((u >> 16) & 1u);           // round-to-nearest-even
    return (unsigned short)(u >> 16);
}

// ---------------------------------------------------------------------------
// ws layout:
//   Qf      : N*DIM floats            (f32: wave-uniform read)
//   Kb,Vb,Cb: N*DIM ushorts each      (bf16: randomly gathered -> 1 line/row)
//   bucket_col : NE ints              (CSR position -> col node)
//   counts  : N ints (doubles as fill cursor)
//   offsets : N+1 ints
//   bsums   : 256 ints
//   wsum    : N floats
//   S       : 1 float
// ---------------------------------------------------------------------------

// QKV projections, 64 nodes/block (f32 in, Q f32 / K,V bf16 out) + coord->bf16
__global__ __launch_bounds__(256) void k_qkv(
    const float* __restrict__ x, const float* __restrict__ coord,
    const float* __restrict__ Wq, const float* __restrict__ bq,
    const float* __restrict__ Wk, const float* __restrict__ bk,
    const float* __restrict__ Wv, const float* __restrict__ bv,
    float* __restrict__ Qf, unsigned short* __restrict__ Kb,
    unsigned short* __restrict__ Vb, unsigned short* __restrict__ Cb)
{
    __shared__ float4 WqT4[1024], WkT4[1024], WvT4[1024];   // 48 KB
    __shared__ float4 xs4[64][16];                          // 16 KB

    const int tid = threadIdx.x;
    const int base = blockIdx.x * 64;
    const float4* Wq4 = (const float4*)Wq;
    const float4* Wk4 = (const float4*)Wk;
    const float4* Wv4 = (const float4*)Wv;
    for (int t = tid; t < 1024; t += 256) {
        int d = t >> 4, j2 = t & 15;
        WqT4[j2 * 64 + d] = Wq4[t];
        WkT4[j2 * 64 + d] = Wk4[t];
        WvT4[j2 * 64 + d] = Wv4[t];
    }
    // coord -> bf16 (64 node rows)
    for (int t = tid; t < 64 * DIM; t += 256) {
        int gn = base + (t >> 6);
        if (gn < N_NODES)
            Cb[(size_t)base * DIM + t] = f2bf(coord[(size_t)base * DIM + t]);
    }
    // stage 64 node rows of x as float4
    for (int t = tid; t < 1024; t += 256) {
        int r = t >> 4, j2 = t & 15;
        if (base + r < N_NODES)
            xs4[r][j2] = ((const float4*)x)[(size_t)(base + r) * 16 + j2];
    }
    __syncthreads();

    const int wv = tid >> 6;   // wave handles 16 nodes
    const int d  = tid & 63;
    const float bqv = bq[d], bkv = bk[d], bvv = bv[d];

    float aq[16], ak[16], av[16];
    #pragma unroll
    for (int r = 0; r < 16; ++r) { aq[r] = bqv; ak[r] = bkv; av[r] = bvv; }

    #pragma unroll
    for (int j2 = 0; j2 < 16; ++j2) {
        float4 wq = WqT4[j2 * 64 + d];
        float4 wk = WkT4[j2 * 64 + d];
        float4 wvv = WvT4[j2 * 64 + d];
        #pragma unroll
        for (int r = 0; r < 16; ++r) {
            float4 xv = xs4[wv * 16 + r][j2];
            aq[r] += xv.x * wq.x + xv.y * wq.y + xv.z * wq.z + xv.w * wq.w;
            ak[r] += xv.x * wk.x + xv.y * wk.y + xv.z * wk.z + xv.w * wk.w;
            av[r] += xv.x * wvv.x + xv.y * wvv.y + xv.z * wvv.z + xv.w * wvv.w;
        }
    }
    #pragma unroll
    for (int r = 0; r < 16; ++r) {
        int n = base + wv * 16 + r;
        if (n < N_NODES) {
            Qf[(size_t)n * DIM + d] = aq[r];
            Kb[(size_t)n * DIM + d] = f2bf(ak[r]);
            Vb[(size_t)n * DIM + d] = f2bf(av[r]);
        }
    }
}

__global__ __launch_bounds__(256) void k_hist(
    const int* __restrict__ eidx, int* __restrict__ counts)
{
    int e = blockIdx.x * 256 + threadIdx.x;
    if (e < NE) atomicAdd(counts + eidx[e], 1);
}

__global__ __launch_bounds__(256) void k_scan1(
    const int* __restrict__ counts, int* __restrict__ offsets,
    int* __restrict__ bsums)
{
    __shared__ int tmp[256];
    int i = blockIdx.x * 256 + threadIdx.x;
    int v = (i < N_NODES) ? counts[i] : 0;
    tmp[threadIdx.x] = v;
    __syncthreads();
    #pragma unroll
    for (int off = 1; off < 256; off <<= 1) {
        int t = (threadIdx.x >= off) ? tmp[threadIdx.x - off] : 0;
        __syncthreads();
        tmp[threadIdx.x] += t;
        __syncthreads();
    }
    if (i < N_NODES) offsets[i] = tmp[threadIdx.x] - v;   // exclusive
    if (threadIdx.x == 255) bsums[blockIdx.x] = tmp[255];
}

__global__ __launch_bounds__(256) void k_scan2(int* __restrict__ bsums)
{
    __shared__ int tmp[256];
    int i = threadIdx.x;
    int v = (i < NSCAN_BLOCKS) ? bsums[i] : 0;
    tmp[i] = v;
    __syncthreads();
    #pragma unroll
    for (int off = 1; off < 256; off <<= 1) {
        int t = (i >= off) ? tmp[i - off] : 0;
        __syncthreads();
        tmp[i] += t;
        __syncthreads();
    }
    if (i < NSCAN_BLOCKS) bsums[i] = tmp[i] - v;
}

__global__ __launch_bounds__(256) void k_scan3(
    int* __restrict__ offsets, int* __restrict__ counts,
    const int* __restrict__ bsums)
{
    int i = blockIdx.x * 256 + threadIdx.x;
    if (i < N_NODES) {
        int o = offsets[i] + bsums[i >> 8];
        offsets[i] = o;
        counts[i]  = o;     // cursor for fill
    }
    if (i == 0) offsets[N_NODES] = NE;
}

__global__ __launch_bounds__(256) void k_fill(
    const int* __restrict__ eidx, int* __restrict__ cursor,
    int* __restrict__ bucket_col)
{
    int e = blockIdx.x * 256 + threadIdx.x;
    if (e < NE) {
        int pos = atomicAdd(cursor + eidx[e], 1);
        bucket_col[pos] = eidx[NE + e];
    }
}

// Fused edge pass: wave per node, 16-lane quarter per edge, lane = 4 dims.
// logit -> exp -> unnormalized accumulate; acc -> d_out, Σp -> wsum.
__global__ __launch_bounds__(256) void k_edge_fused(
    const int* __restrict__ bucket_col, const int* __restrict__ offsets,
    const float* __restrict__ Qf, const unsigned short* __restrict__ Kb,
    const unsigned short* __restrict__ Vb, const unsigned short* __restrict__ Cb,
    const float* __restrict__ coord,
    const float* __restrict__ Wc, const float* __restrict__ bc,
    float* __restrict__ out_x, float* __restrict__ out_c,
    float* __restrict__ wsum)
{
    const int lane = threadIdx.x & 63;
    const int n = (blockIdx.x * 256 + threadIdx.x) >> 6;
    if (n >= N_NODES) return;
    const int qt = lane >> 4;          // quarter: which edge of the group of 4
    const int sl = lane & 15;          // dim-quad slot (dims 4sl..4sl+3)

    const float4 q4  = ((const float4*)Qf)[(size_t)n * 16 + sl];
    const float4 cr4 = ((const float4*)coord)[(size_t)n * 16 + sl];
    const float4 wc4 = ((const float4*)Wc)[sl];
    const float4 bc4 = ((const float4*)bc)[sl];

    const int s = offsets[n], t = offsets[n + 1];
    float4 accx = {0.f, 0.f, 0.f, 0.f};
    float4 accc = {0.f, 0.f, 0.f, 0.f};
    float psum = 0.0f;

    for (int base = s; base < t; base += 4) {
        int pos = base + qt;
        bool valid = pos < t;
        int pc = valid ? pos : (t - 1);          // duplicate-safe clamp
        int c = bucket_col[pc];                  // same addr across quarter
        size_t rb = (size_t)c * 16 + sl;         // ushort4 units: 1 line/row
        ushort4 ku = ((const ushort4*)Kb)[rb];
        ushort4 vu = ((const ushort4*)Vb)[rb];
        ushort4 cu = ((const ushort4*)Cb)[rb];
        float kx = bf2f(ku.x), ky = bf2f(ku.y), kz = bf2f(ku.z), kw = bf2f(ku.w);
        float vx = bf2f(vu.x), vy = bf2f(vu.y), vz = bf2f(vu.z), vw = bf2f(vu.w);
        float cx = bf2f(cu.x), cy = bf2f(cu.y), cz = bf2f(cu.z), cw = bf2f(cu.w);

        float d = q4.x * kx + q4.y * ky + q4.z * kz + q4.w * kw;
        float dxx = cr4.x - cx, dxy = cr4.y - cy;
        float dxz = cr4.z - cz, dxw = cr4.w - cw;
        float e = dxx * dxx + dxy * dxy + dxz * dxz + dxw * dxw;
        #pragma unroll
        for (int off = 1; off <= 8; off <<= 1) {   // reduce within quarter
            d += __shfl_xor(d, off);
            e += __shfl_xor(e, off);
        }
        float p = valid ? __expf(d) : 0.0f;
        float dist = sqrtf(e);
        psum += p;
        accx.x += p * vx; accx.y += p * vy;
        accx.z += p * vz; accx.w += p * vw;
        float gx = dist * wc4.x + bc4.x;
        float gy = dist * wc4.y + bc4.y;
        float gz = dist * wc4.z + bc4.z;
        float gw = dist * wc4.w + bc4.w;
        accc.x += p * gx * dxx; accc.y += p * gy * dxy;
        accc.z += p * gz * dxz; accc.w += p * gw * dxw;
    }

    // cross-quarter combine (once per node)
    #pragma unroll
    for (int off = 16; off <= 32; off <<= 1) {
        accx.x += __shfl_xor(accx.x, off);
        accx.y += __shfl_xor(accx.y, off);
        accx.z += __shfl_xor(accx.z, off);
        accx.w += __shfl_xor(accx.w, off);
        accc.x += __shfl_xor(accc.x, off);
        accc.y += __shfl_xor(accc.y, off);
        accc.z += __shfl_xor(accc.z, off);
        accc.w += __shfl_xor(accc.w, off);
        psum   += __shfl_xor(psum, off);
    }
    if (lane < 16) {
        ((float4*)out_x)[(size_t)n * 16 + sl] = accx;   // unnormalized
        ((float4*)out_c)[(size_t)n * 16 + sl] = accc;
    }
    if (lane == 0) wsum[n] = psum;
}

// deterministic fixed-tree reduction of wsum -> S (single block)
__global__ __launch_bounds__(1024) void k_redsum(
    const float* __restrict__ wsum, float* __restrict__ S)
{
    __shared__ float red[16];
    float a = 0.0f;
    for (int i = threadIdx.x; i < N_NODES; i += 1024) a += wsum[i];
    #pragma unroll
    for (int off = 32; off; off >>= 1) a += __shfl_xor(a, off);
    if ((threadIdx.x & 63) == 0) red[threadIdx.x >> 6] = a;
    __syncthreads();
    if (threadIdx.x == 0) {
        float s = 0.0f;
        #pragma unroll
        for (int w = 0; w < 16; ++w) s += red[w];
        *S = s;
    }
}

// out = residual + out * (1/S), vectorized float4
__global__ __launch_bounds__(256) void k_finalize(
    const float* __restrict__ x, const float* __restrict__ coord,
    const float* __restrict__ S, float* __restrict__ out)
{
    const float inv = 1.0f / *S;
    const int nd4 = (N_NODES * DIM) / 4;      // 800000
    const float4* x4 = (const float4*)x;
    const float4* c4 = (const float4*)coord;
    float4* o4 = (float4*)out;
    for (int i = blockIdx.x * 256 + threadIdx.x; i < 2 * nd4;
         i += gridDim.x * 256) {
        float4 r = (i < nd4) ? x4[i] : c4[i - nd4];
        float4 a = o4[i];
        a.x = r.x + a.x * inv;
        a.y = r.y + a.y * inv;
        a.z = r.z + a.z * inv;
        a.w = r.w + a.w * inv;
        o4[i] = a;
    }
}

extern "C" void kernel_launch(void* const* d_in, const int* in_sizes, int n_in,
                              void* d_out, int out_size, void* d_ws, size_t ws_size,
                              hipStream_t stream)
{
    const float* x     = (const float*)d_in[0];
    const float* coord = (const float*)d_in[1];
    const float* Wq    = (const float*)d_in[2];
    const float* bq    = (const float*)d_in[3];
    const float* Wk    = (const float*)d_in[4];
    const float* bk    = (const float*)d_in[5];
    const float* Wv    = (const float*)d_in[6];
    const float* bv    = (const float*)d_in[7];
    const float* Wc    = (const float*)d_in[8];
    const float* bc    = (const float*)d_in[9];
    const int*   eidx  = (const int*)d_in[10];

    float* out = (float*)d_out;
    float* ws  = (float*)d_ws;

    float* Qf = ws;
    unsigned short* Kb = (unsigned short*)(Qf + (size_t)N_NODES * DIM);
    unsigned short* Vb = Kb + (size_t)N_NODES * DIM;
    unsigned short* Cb = Vb + (size_t)N_NODES * DIM;
    int* bucket_col = (int*)(Cb + (size_t)N_NODES * DIM);
    int* counts  = bucket_col + NE;
    int* offsets = counts + N_NODES;
    int* bsums   = offsets + N_NODES + 1;
    float* wsum  = (float*)(bsums + 256);
    float* S     = wsum + N_NODES;

    float* out_x = out;
    float* out_c = out + (size_t)N_NODES * DIM;

    // CSR build (row-bucketed column list)
    hipMemsetAsync(counts, 0, (size_t)N_NODES * sizeof(int), stream);
    k_hist <<<(NE + 255) / 256, 256, 0, stream>>>(eidx, counts);
    k_scan1<<<NSCAN_BLOCKS, 256, 0, stream>>>(counts, offsets, bsums);
    k_scan2<<<1, 256, 0, stream>>>(bsums);
    k_scan3<<<NSCAN_BLOCKS, 256, 0, stream>>>(offsets, counts, bsums);
    k_fill <<<(NE + 255) / 256, 256, 0, stream>>>(eidx, counts, bucket_col);

    // node projections + bf16 packing (64 nodes/block)
    k_qkv<<<(N_NODES + 63) / 64, 256, 0, stream>>>(
        x, coord, Wq, bq, Wk, bk, Wv, bv, Qf, Kb, Vb, Cb);

    // fused edge pass (quarter-per-edge), acc -> d_out, Σp -> wsum
    k_edge_fused<<<(N_NODES * 64 + 255) / 256, 256, 0, stream>>>(
        bucket_col, offsets, Qf, Kb, Vb, Cb, coord, Wc, bc,
        out_x, out_c, wsum);

    // deterministic global sum, then normalize + residual
    k_redsum<<<1, 1024, 0, stream>>>(wsum, S);
    k_finalize<<<2048, 256, 0, stream>>>(x, coord, S, out);
}

// Round 6
// 265.896 us; speedup vs baseline: 2.4132x; 2.4132x over previous
//
#include <hip/hip_runtime.h>
#include <math.h>

#define N_NODES 50000
#define DIM 64
#define NE 800000
#define NSCAN_BLOCKS ((N_NODES + 255) / 256)   // 196

static __device__ __forceinline__ float bf2f(unsigned short u) {
    return __uint_as_float(((unsigned int)u) << 16);
}
static __device__ __forceinline__ unsigned short f2bf(float f) {
    unsigned int u = __float_as_uint(f);
    u += 0x7fffu + ((u >> 16) & 1u);           // round-to-nearest-even
    return (unsigned short)(u >> 16);
}

// ---------------------------------------------------------------------------
// ws layout:
//   Qf      : N*DIM floats            (f32: wave-uniform read)
//   Kb,Vb,Cb: N*DIM ushorts each      (bf16: randomly gathered -> 1 line/row)
//   bucket_col : NE ints              (CSR position -> col node)
//   counts  : N ints (doubles as fill cursor)
//   offsets : N+1 ints
//   bsums   : 256 ints
//   wsum    : N floats
//   S       : 1 float
// ---------------------------------------------------------------------------

// QKV projections, 16 nodes/block, 4 accum/thread (proven R4 config:
// VGPR ~110, 52KB LDS, ~27us). 64-node/16-accum variant spilled (VGPR=256).
__global__ __launch_bounds__(256) void k_qkv(
    const float* __restrict__ x, const float* __restrict__ coord,
    const float* __restrict__ Wq, const float* __restrict__ bq,
    const float* __restrict__ Wk, const float* __restrict__ bk,
    const float* __restrict__ Wv, const float* __restrict__ bv,
    float* __restrict__ Qf, unsigned short* __restrict__ Kb,
    unsigned short* __restrict__ Vb, unsigned short* __restrict__ Cb)
{
    __shared__ float4 WqT4[1024], WkT4[1024], WvT4[1024];
    __shared__ float4 xs4[16][16];

    const int tid = threadIdx.x;
    const float4* Wq4 = (const float4*)Wq;
    const float4* Wk4 = (const float4*)Wk;
    const float4* Wv4 = (const float4*)Wv;
    for (int t = tid; t < 1024; t += 256) {
        int d = t >> 4, j2 = t & 15;
        WqT4[j2 * 64 + d] = Wq4[t];
        WkT4[j2 * 64 + d] = Wk4[t];
        WvT4[j2 * 64 + d] = Wv4[t];
    }

    const int base = blockIdx.x * 16;

    // coord -> bf16 (16 node rows, contiguous)
    for (int t = tid; t < 16 * DIM; t += 256) {
        int gn = base + (t >> 6);
        if (gn < N_NODES)
            Cb[(size_t)base * DIM + t] = f2bf(coord[(size_t)base * DIM + t]);
    }

    {   // stage 16 node rows of x as float4
        int r = tid >> 4, j2 = tid & 15;
        if (base + r < N_NODES)
            xs4[r][j2] = ((const float4*)x)[(size_t)(base + r) * 16 + j2];
    }
    __syncthreads();

    const int wv = tid >> 6;
    const int d  = tid & 63;
    const float bqv = bq[d], bkv = bk[d], bvv = bv[d];

    float aq[4], ak[4], av[4];
    #pragma unroll
    for (int r = 0; r < 4; ++r) { aq[r] = bqv; ak[r] = bkv; av[r] = bvv; }

    #pragma unroll
    for (int j2 = 0; j2 < 16; ++j2) {
        float4 wq = WqT4[j2 * 64 + d];
        float4 wk = WkT4[j2 * 64 + d];
        float4 wvv = WvT4[j2 * 64 + d];
        #pragma unroll
        for (int r = 0; r < 4; ++r) {
            float4 xv = xs4[wv * 4 + r][j2];
            aq[r] += xv.x * wq.x + xv.y * wq.y + xv.z * wq.z + xv.w * wq.w;
            ak[r] += xv.x * wk.x + xv.y * wk.y + xv.z * wk.z + xv.w * wk.w;
            av[r] += xv.x * wvv.x + xv.y * wvv.y + xv.z * wvv.z + xv.w * wvv.w;
        }
    }
    #pragma unroll
    for (int r = 0; r < 4; ++r) {
        int n = base + wv * 4 + r;
        if (n < N_NODES) {
            Qf[(size_t)n * DIM + d] = aq[r];
            Kb[(size_t)n * DIM + d] = f2bf(ak[r]);
            Vb[(size_t)n * DIM + d] = f2bf(av[r]);
        }
    }
}

__global__ __launch_bounds__(256) void k_hist(
    const int* __restrict__ eidx, int* __restrict__ counts)
{
    int e = blockIdx.x * 256 + threadIdx.x;
    if (e < NE) atomicAdd(counts + eidx[e], 1);
}

__global__ __launch_bounds__(256) void k_scan1(
    const int* __restrict__ counts, int* __restrict__ offsets,
    int* __restrict__ bsums)
{
    __shared__ int tmp[256];
    int i = blockIdx.x * 256 + threadIdx.x;
    int v = (i < N_NODES) ? counts[i] : 0;
    tmp[threadIdx.x] = v;
    __syncthreads();
    #pragma unroll
    for (int off = 1; off < 256; off <<= 1) {
        int t = (threadIdx.x >= off) ? tmp[threadIdx.x - off] : 0;
        __syncthreads();
        tmp[threadIdx.x] += t;
        __syncthreads();
    }
    if (i < N_NODES) offsets[i] = tmp[threadIdx.x] - v;   // exclusive
    if (threadIdx.x == 255) bsums[blockIdx.x] = tmp[255];
}

__global__ __launch_bounds__(256) void k_scan2(int* __restrict__ bsums)
{
    __shared__ int tmp[256];
    int i = threadIdx.x;
    int v = (i < NSCAN_BLOCKS) ? bsums[i] : 0;
    tmp[i] = v;
    __syncthreads();
    #pragma unroll
    for (int off = 1; off < 256; off <<= 1) {
        int t = (i >= off) ? tmp[i - off] : 0;
        __syncthreads();
        tmp[i] += t;
        __syncthreads();
    }
    if (i < NSCAN_BLOCKS) bsums[i] = tmp[i] - v;
}

__global__ __launch_bounds__(256) void k_scan3(
    int* __restrict__ offsets, int* __restrict__ counts,
    const int* __restrict__ bsums)
{
    int i = blockIdx.x * 256 + threadIdx.x;
    if (i < N_NODES) {
        int o = offsets[i] + bsums[i >> 8];
        offsets[i] = o;
        counts[i]  = o;     // cursor for fill
    }
    if (i == 0) offsets[N_NODES] = NE;
}

__global__ __launch_bounds__(256) void k_fill(
    const int* __restrict__ eidx, int* __restrict__ cursor,
    int* __restrict__ bucket_col)
{
    int e = blockIdx.x * 256 + threadIdx.x;
    if (e < NE) {
        int pos = atomicAdd(cursor + eidx[e], 1);
        bucket_col[pos] = eidx[NE + e];
    }
}

// Fused edge pass: wave per node, 16-lane quarter per edge, lane = 4 dims.
// logit -> exp -> unnormalized accumulate; acc -> d_out, Σp -> wsum.
__global__ __launch_bounds__(256) void k_edge_fused(
    const int* __restrict__ bucket_col, const int* __restrict__ offsets,
    const float* __restrict__ Qf, const unsigned short* __restrict__ Kb,
    const unsigned short* __restrict__ Vb, const unsigned short* __restrict__ Cb,
    const float* __restrict__ coord,
    const float* __restrict__ Wc, const float* __restrict__ bc,
    float* __restrict__ out_x, float* __restrict__ out_c,
    float* __restrict__ wsum)
{
    const int lane = threadIdx.x & 63;
    const int n = (blockIdx.x * 256 + threadIdx.x) >> 6;
    if (n >= N_NODES) return;
    const int qt = lane >> 4;          // quarter: which edge of the group of 4
    const int sl = lane & 15;          // dim-quad slot (dims 4sl..4sl+3)

    const float4 q4  = ((const float4*)Qf)[(size_t)n * 16 + sl];
    const float4 cr4 = ((const float4*)coord)[(size_t)n * 16 + sl];
    const float4 wc4 = ((const float4*)Wc)[sl];
    const float4 bc4 = ((const float4*)bc)[sl];

    const int s = offsets[n], t = offsets[n + 1];
    float4 accx = {0.f, 0.f, 0.f, 0.f};
    float4 accc = {0.f, 0.f, 0.f, 0.f};
    float psum = 0.0f;

    for (int base = s; base < t; base += 4) {
        int pos = base + qt;
        bool valid = pos < t;
        int pc = valid ? pos : (t - 1);          // duplicate-safe clamp
        int c = bucket_col[pc];                  // same addr across quarter
        size_t rb = (size_t)c * 16 + sl;         // ushort4 units: 1 line/row
        ushort4 ku = ((const ushort4*)Kb)[rb];
        ushort4 vu = ((const ushort4*)Vb)[rb];
        ushort4 cu = ((const ushort4*)Cb)[rb];
        float kx = bf2f(ku.x), ky = bf2f(ku.y), kz = bf2f(ku.z), kw = bf2f(ku.w);
        float vx = bf2f(vu.x), vy = bf2f(vu.y), vz = bf2f(vu.z), vw = bf2f(vu.w);
        float cx = bf2f(cu.x), cy = bf2f(cu.y), cz = bf2f(cu.z), cw = bf2f(cu.w);

        float d = q4.x * kx + q4.y * ky + q4.z * kz + q4.w * kw;
        float dxx = cr4.x - cx, dxy = cr4.y - cy;
        float dxz = cr4.z - cz, dxw = cr4.w - cw;
        float e = dxx * dxx + dxy * dxy + dxz * dxz + dxw * dxw;
        #pragma unroll
        for (int off = 1; off <= 8; off <<= 1) {   // reduce within quarter
            d += __shfl_xor(d, off);
            e += __shfl_xor(e, off);
        }
        float p = valid ? __expf(d) : 0.0f;
        float dist = sqrtf(e);
        psum += p;
        accx.x += p * vx; accx.y += p * vy;
        accx.z += p * vz; accx.w += p * vw;
        float gx = dist * wc4.x + bc4.x;
        float gy = dist * wc4.y + bc4.y;
        float gz = dist * wc4.z + bc4.z;
        float gw = dist * wc4.w + bc4.w;
        accc.x += p * gx * dxx; accc.y += p * gy * dxy;
        accc.z += p * gz * dxz; accc.w += p * gw * dxw;
    }

    // cross-quarter combine (once per node)
    #pragma unroll
    for (int off = 16; off <= 32; off <<= 1) {
        accx.x += __shfl_xor(accx.x, off);
        accx.y += __shfl_xor(accx.y, off);
        accx.z += __shfl_xor(accx.z, off);
        accx.w += __shfl_xor(accx.w, off);
        accc.x += __shfl_xor(accc.x, off);
        accc.y += __shfl_xor(accc.y, off);
        accc.z += __shfl_xor(accc.z, off);
        accc.w += __shfl_xor(accc.w, off);
        psum   += __shfl_xor(psum, off);
    }
    if (lane < 16) {
        ((float4*)out_x)[(size_t)n * 16 + sl] = accx;   // unnormalized
        ((float4*)out_c)[(size_t)n * 16 + sl] = accc;
    }
    if (lane == 0) wsum[n] = psum;
}

// deterministic fixed-tree reduction of wsum -> S (single block)
__global__ __launch_bounds__(1024) void k_redsum(
    const float* __restrict__ wsum, float* __restrict__ S)
{
    __shared__ float red[16];
    float a = 0.0f;
    for (int i = threadIdx.x; i < N_NODES; i += 1024) a += wsum[i];
    #pragma unroll
    for (int off = 32; off; off >>= 1) a += __shfl_xor(a, off);
    if ((threadIdx.x & 63) == 0) red[threadIdx.x >> 6] = a;
    __syncthreads();
    if (threadIdx.x == 0) {
        float s = 0.0f;
        #pragma unroll
        for (int w = 0; w < 16; ++w) s += red[w];
        *S = s;
    }
}

// out = residual + out * (1/S), vectorized float4
__global__ __launch_bounds__(256) void k_finalize(
    const float* __restrict__ x, const float* __restrict__ coord,
    const float* __restrict__ S, float* __restrict__ out)
{
    const float inv = 1.0f / *S;
    const int nd4 = (N_NODES * DIM) / 4;      // 800000
    const float4* x4 = (const float4*)x;
    const float4* c4 = (const float4*)coord;
    float4* o4 = (float4*)out;
    for (int i = blockIdx.x * 256 + threadIdx.x; i < 2 * nd4;
         i += gridDim.x * 256) {
        float4 r = (i < nd4) ? x4[i] : c4[i - nd4];
        float4 a = o4[i];
        a.x = r.x + a.x * inv;
        a.y = r.y + a.y * inv;
        a.z = r.z + a.z * inv;
        a.w = r.w + a.w * inv;
        o4[i] = a;
    }
}

extern "C" void kernel_launch(void* const* d_in, const int* in_sizes, int n_in,
                              void* d_out, int out_size, void* d_ws, size_t ws_size,
                              hipStream_t stream)
{
    const float* x     = (const float*)d_in[0];
    const float* coord = (const float*)d_in[1];
    const float* Wq    = (const float*)d_in[2];
    const float* bq    = (const float*)d_in[3];
    const float* Wk    = (const float*)d_in[4];
    const float* bk    = (const float*)d_in[5];
    const float* Wv    = (const float*)d_in[6];
    const float* bv    = (const float*)d_in[7];
    const float* Wc    = (const float*)d_in[8];
    const float* bc    = (const float*)d_in[9];
    const int*   eidx  = (const int*)d_in[10];

    float* out = (float*)d_out;
    float* ws  = (float*)d_ws;

    float* Qf = ws;
    unsigned short* Kb = (unsigned short*)(Qf + (size_t)N_NODES * DIM);
    unsigned short* Vb = Kb + (size_t)N_NODES * DIM;
    unsigned short* Cb = Vb + (size_t)N_NODES * DIM;
    int* bucket_col = (int*)(Cb + (size_t)N_NODES * DIM);
    int* counts  = bucket_col + NE;
    int* offsets = counts + N_NODES;
    int* bsums   = offsets + N_NODES + 1;
    float* wsum  = (float*)(bsums + 256);
    float* S     = wsum + N_NODES;

    float* out_x = out;
    float* out_c = out + (size_t)N_NODES * DIM;

    // CSR build (row-bucketed column list)
    hipMemsetAsync(counts, 0, (size_t)N_NODES * sizeof(int), stream);
    k_hist <<<(NE + 255) / 256, 256, 0, stream>>>(eidx, counts);
    k_scan1<<<NSCAN_BLOCKS, 256, 0, stream>>>(counts, offsets, bsums);
    k_scan2<<<1, 256, 0, stream>>>(bsums);
    k_scan3<<<NSCAN_BLOCKS, 256, 0, stream>>>(offsets, counts, bsums);
    k_fill <<<(NE + 255) / 256, 256, 0, stream>>>(eidx, counts, bucket_col);

    // node projections + bf16 packing (16 nodes/block — proven config)
    k_qkv<<<(N_NODES + 15) / 16, 256, 0, stream>>>(
        x, coord, Wq, bq, Wk, bk, Wv, bv, Qf, Kb, Vb, Cb);

    // fused edge pass (quarter-per-edge), acc -> d_out, Σp -> wsum
    k_edge_fused<<<(N_NODES * 64 + 255) / 256, 256, 0, stream>>>(
        bucket_col, offsets, Qf, Kb, Vb, Cb, coord, Wc, bc,
        out_x, out_c, wsum);

    // deterministic global sum, then normalize + residual
    k_redsum<<<1, 1024, 0, stream>>>(wsum, S);
    k_finalize<<<2048, 256, 0, stream>>>(x, coord, S, out);
}

// Round 7
// 229.811 us; speedup vs baseline: 2.7921x; 1.1570x over previous
//
#include <hip/hip_runtime.h>
#include <math.h>

#define N_NODES 50000
#define DIM 64
#define NE 800000
#define NSCAN_BLOCKS ((N_NODES + 255) / 256)   // 196
#define QKV_BLOCKS 448

static __device__ __forceinline__ float bf2f(unsigned short u) {
    return __uint_as_float(((unsigned int)u) << 16);
}
static __device__ __forceinline__ unsigned short f2bf(float f) {
    unsigned int u = __float_as_uint(f);
    u += 0x7fffu + ((u >> 16) & 1u);           // round-to-nearest-even
    return (unsigned short)(u >> 16);
}

// ---------------------------------------------------------------------------
// ws layout:
//   Qf      : N*DIM floats            (f32: wave-uniform read)
//   Kb,Vb,Cb: N*DIM ushorts each      (bf16: randomly gathered -> 1 line/row)
//   bucket_col : NE ints              (CSR position -> col node)
//   counts  : N ints (doubles as fill cursor)
//   offsets : N+1 ints
//   bsums   : 256 ints
//   wsum    : N floats
//   S       : 1 float
// ---------------------------------------------------------------------------

// QKV projections: PERSISTENT blocks — weights staged once per block
// (conflict-free consecutive LDS writes), then loop over 16-node tiles.
__global__ __launch_bounds__(256, 3) void k_qkv(
    const float* __restrict__ x, const float* __restrict__ coord,
    const float* __restrict__ Wq, const float* __restrict__ bq,
    const float* __restrict__ Wk, const float* __restrict__ bk,
    const float* __restrict__ Wv, const float* __restrict__ bv,
    float* __restrict__ Qf, unsigned short* __restrict__ Kb,
    unsigned short* __restrict__ Vb, unsigned short* __restrict__ Cb)
{
    __shared__ float4 WT4[3][1024];   // 48 KB: WT4[m][j2*64+d] = W[d][4j2..]
    __shared__ float4 xs4[16][16];    // 4 KB

    const int tid = threadIdx.x;
    // Stage weights once. Dest index t is consecutive per lane -> no bank
    // conflicts on the LDS write; the strided global read (stride 256B)
    // happens only QKV_BLOCKS times -> L2-trivial.
    for (int t = tid; t < 1024; t += 256) {
        int d = t & 63, j2 = t >> 6;
        WT4[0][t] = ((const float4*)Wq)[d * 16 + j2];
        WT4[1][t] = ((const float4*)Wk)[d * 16 + j2];
        WT4[2][t] = ((const float4*)Wv)[d * 16 + j2];
    }

    const int wv = tid >> 6;
    const int d  = tid & 63;
    const float bqv = bq[d], bkv = bk[d], bvv = bv[d];

    for (int tile = blockIdx.x; tile * 16 < N_NODES; tile += QKV_BLOCKS) {
        const int base = tile * 16;
        __syncthreads();   // protect xs4 readers of previous tile (and
                           // orders first-tile compute after weight staging)
        {   // stage 16 node rows of x as float4
            int r = tid >> 4, j2 = tid & 15;
            if (base + r < N_NODES)
                xs4[r][j2] = ((const float4*)x)[(size_t)(base + r) * 16 + j2];
        }
        // coord -> bf16 for this tile (global->global, coalesced)
        for (int t = tid; t < 16 * DIM; t += 256) {
            if (base + (t >> 6) < N_NODES)
                Cb[(size_t)base * DIM + t] =
                    f2bf(coord[(size_t)base * DIM + t]);
        }
        __syncthreads();

        float aq[4], ak[4], av[4];
        #pragma unroll
        for (int r = 0; r < 4; ++r) { aq[r] = bqv; ak[r] = bkv; av[r] = bvv; }

        #pragma unroll 4
        for (int j2 = 0; j2 < 16; ++j2) {
            float4 wq = WT4[0][j2 * 64 + d];
            float4 wk = WT4[1][j2 * 64 + d];
            float4 wvv = WT4[2][j2 * 64 + d];
            #pragma unroll
            for (int r = 0; r < 4; ++r) {
                float4 xv = xs4[wv * 4 + r][j2];
                aq[r] += xv.x * wq.x + xv.y * wq.y + xv.z * wq.z + xv.w * wq.w;
                ak[r] += xv.x * wk.x + xv.y * wk.y + xv.z * wk.z + xv.w * wk.w;
                av[r] += xv.x * wvv.x + xv.y * wvv.y + xv.z * wvv.z + xv.w * wvv.w;
            }
        }
        #pragma unroll
        for (int r = 0; r < 4; ++r) {
            int n = base + wv * 4 + r;
            if (n < N_NODES) {
                Qf[(size_t)n * DIM + d] = aq[r];
                Kb[(size_t)n * DIM + d] = f2bf(ak[r]);
                Vb[(size_t)n * DIM + d] = f2bf(av[r]);
            }
        }
    }
}

__global__ __launch_bounds__(256) void k_hist(
    const int* __restrict__ eidx, int* __restrict__ counts)
{
    int e = blockIdx.x * 256 + threadIdx.x;
    if (e < NE) atomicAdd(counts + eidx[e], 1);
}

__global__ __launch_bounds__(256) void k_scan1(
    const int* __restrict__ counts, int* __restrict__ offsets,
    int* __restrict__ bsums)
{
    __shared__ int tmp[256];
    int i = blockIdx.x * 256 + threadIdx.x;
    int v = (i < N_NODES) ? counts[i] : 0;
    tmp[threadIdx.x] = v;
    __syncthreads();
    #pragma unroll
    for (int off = 1; off < 256; off <<= 1) {
        int t = (threadIdx.x >= off) ? tmp[threadIdx.x - off] : 0;
        __syncthreads();
        tmp[threadIdx.x] += t;
        __syncthreads();
    }
    if (i < N_NODES) offsets[i] = tmp[threadIdx.x] - v;   // exclusive
    if (threadIdx.x == 255) bsums[blockIdx.x] = tmp[255];
}

__global__ __launch_bounds__(256) void k_scan2(int* __restrict__ bsums)
{
    __shared__ int tmp[256];
    int i = threadIdx.x;
    int v = (i < NSCAN_BLOCKS) ? bsums[i] : 0;
    tmp[i] = v;
    __syncthreads();
    #pragma unroll
    for (int off = 1; off < 256; off <<= 1) {
        int t = (i >= off) ? tmp[i - off] : 0;
        __syncthreads();
        tmp[i] += t;
        __syncthreads();
    }
    if (i < NSCAN_BLOCKS) bsums[i] = tmp[i] - v;
}

__global__ __launch_bounds__(256) void k_scan3(
    int* __restrict__ offsets, int* __restrict__ counts,
    const int* __restrict__ bsums)
{
    int i = blockIdx.x * 256 + threadIdx.x;
    if (i < N_NODES) {
        int o = offsets[i] + bsums[i >> 8];
        offsets[i] = o;
        counts[i]  = o;     // cursor for fill
    }
    if (i == 0) offsets[N_NODES] = NE;
}

__global__ __launch_bounds__(256) void k_fill(
    const int* __restrict__ eidx, int* __restrict__ cursor,
    int* __restrict__ bucket_col)
{
    int e = blockIdx.x * 256 + threadIdx.x;
    if (e < NE) {
        int pos = atomicAdd(cursor + eidx[e], 1);
        bucket_col[pos] = eidx[NE + e];
    }
}

// Fused edge pass: wave per node, 16-lane quarter per edge, lane = 4 dims.
// logit -> exp -> unnormalized accumulate; acc -> d_out, Σp -> wsum.
__global__ __launch_bounds__(256) void k_edge_fused(
    const int* __restrict__ bucket_col, const int* __restrict__ offsets,
    const float* __restrict__ Qf, const unsigned short* __restrict__ Kb,
    const unsigned short* __restrict__ Vb, const unsigned short* __restrict__ Cb,
    const float* __restrict__ coord,
    const float* __restrict__ Wc, const float* __restrict__ bc,
    float* __restrict__ out_x, float* __restrict__ out_c,
    float* __restrict__ wsum)
{
    const int lane = threadIdx.x & 63;
    const int n = (blockIdx.x * 256 + threadIdx.x) >> 6;
    if (n >= N_NODES) return;
    const int qt = lane >> 4;          // quarter: which edge of the group of 4
    const int sl = lane & 15;          // dim-quad slot (dims 4sl..4sl+3)

    const float4 q4  = ((const float4*)Qf)[(size_t)n * 16 + sl];
    const float4 cr4 = ((const float4*)coord)[(size_t)n * 16 + sl];
    const float4 wc4 = ((const float4*)Wc)[sl];
    const float4 bc4 = ((const float4*)bc)[sl];

    const int s = offsets[n], t = offsets[n + 1];
    float4 accx = {0.f, 0.f, 0.f, 0.f};
    float4 accc = {0.f, 0.f, 0.f, 0.f};
    float psum = 0.0f;

    for (int base = s; base < t; base += 4) {
        int pos = base + qt;
        bool valid = pos < t;
        int pc = valid ? pos : (t - 1);          // duplicate-safe clamp
        int c = bucket_col[pc];                  // same addr across quarter
        size_t rb = (size_t)c * 16 + sl;         // ushort4 units: 1 line/row
        ushort4 ku = ((const ushort4*)Kb)[rb];
        ushort4 vu = ((const ushort4*)Vb)[rb];
        ushort4 cu = ((const ushort4*)Cb)[rb];
        float kx = bf2f(ku.x), ky = bf2f(ku.y), kz = bf2f(ku.z), kw = bf2f(ku.w);
        float vx = bf2f(vu.x), vy = bf2f(vu.y), vz = bf2f(vu.z), vw = bf2f(vu.w);
        float cx = bf2f(cu.x), cy = bf2f(cu.y), cz = bf2f(cu.z), cw = bf2f(cu.w);

        float d = q4.x * kx + q4.y * ky + q4.z * kz + q4.w * kw;
        float dxx = cr4.x - cx, dxy = cr4.y - cy;
        float dxz = cr4.z - cz, dxw = cr4.w - cw;
        float e = dxx * dxx + dxy * dxy + dxz * dxz + dxw * dxw;
        #pragma unroll
        for (int off = 1; off <= 8; off <<= 1) {   // reduce within quarter
            d += __shfl_xor(d, off);
            e += __shfl_xor(e, off);
        }
        float p = valid ? __expf(d) : 0.0f;
        float dist = sqrtf(e);
        psum += p;
        accx.x += p * vx; accx.y += p * vy;
        accx.z += p * vz; accx.w += p * vw;
        float gx = dist * wc4.x + bc4.x;
        float gy = dist * wc4.y + bc4.y;
        float gz = dist * wc4.z + bc4.z;
        float gw = dist * wc4.w + bc4.w;
        accc.x += p * gx * dxx; accc.y += p * gy * dxy;
        accc.z += p * gz * dxz; accc.w += p * gw * dxw;
    }

    // cross-quarter combine (once per node)
    #pragma unroll
    for (int off = 16; off <= 32; off <<= 1) {
        accx.x += __shfl_xor(accx.x, off);
        accx.y += __shfl_xor(accx.y, off);
        accx.z += __shfl_xor(accx.z, off);
        accx.w += __shfl_xor(accx.w, off);
        accc.x += __shfl_xor(accc.x, off);
        accc.y += __shfl_xor(accc.y, off);
        accc.z += __shfl_xor(accc.z, off);
        accc.w += __shfl_xor(accc.w, off);
        psum   += __shfl_xor(psum, off);
    }
    if (lane < 16) {
        ((float4*)out_x)[(size_t)n * 16 + sl] = accx;   // unnormalized
        ((float4*)out_c)[(size_t)n * 16 + sl] = accc;
    }
    if (lane == 0) wsum[n] = psum;
}

// deterministic fixed-tree reduction of wsum -> S (single block)
__global__ __launch_bounds__(1024) void k_redsum(
    const float* __restrict__ wsum, float* __restrict__ S)
{
    __shared__ float red[16];
    float a = 0.0f;
    for (int i = threadIdx.x; i < N_NODES; i += 1024) a += wsum[i];
    #pragma unroll
    for (int off = 32; off; off >>= 1) a += __shfl_xor(a, off);
    if ((threadIdx.x & 63) == 0) red[threadIdx.x >> 6] = a;
    __syncthreads();
    if (threadIdx.x == 0) {
        float s = 0.0f;
        #pragma unroll
        for (int w = 0; w < 16; ++w) s += red[w];
        *S = s;
    }
}

// out = residual + out * (1/S), vectorized float4
__global__ __launch_bounds__(256) void k_finalize(
    const float* __restrict__ x, const float* __restrict__ coord,
    const float* __restrict__ S, float* __restrict__ out)
{
    const float inv = 1.0f / *S;
    const int nd4 = (N_NODES * DIM) / 4;      // 800000
    const float4* x4 = (const float4*)x;
    const float4* c4 = (const float4*)coord;
    float4* o4 = (float4*)out;
    for (int i = blockIdx.x * 256 + threadIdx.x; i < 2 * nd4;
         i += gridDim.x * 256) {
        float4 r = (i < nd4) ? x4[i] : c4[i - nd4];
        float4 a = o4[i];
        a.x = r.x + a.x * inv;
        a.y = r.y + a.y * inv;
        a.z = r.z + a.z * inv;
        a.w = r.w + a.w * inv;
        o4[i] = a;
    }
}

extern "C" void kernel_launch(void* const* d_in, const int* in_sizes, int n_in,
                              void* d_out, int out_size, void* d_ws, size_t ws_size,
                              hipStream_t stream)
{
    const float* x     = (const float*)d_in[0];
    const float* coord = (const float*)d_in[1];
    const float* Wq    = (const float*)d_in[2];
    const float* bq    = (const float*)d_in[3];
    const float* Wk    = (const float*)d_in[4];
    const float* bk    = (const float*)d_in[5];
    const float* Wv    = (const float*)d_in[6];
    const float* bv    = (const float*)d_in[7];
    const float* Wc    = (const float*)d_in[8];
    const float* bc    = (const float*)d_in[9];
    const int*   eidx  = (const int*)d_in[10];

    float* out = (float*)d_out;
    float* ws  = (float*)d_ws;

    float* Qf = ws;
    unsigned short* Kb = (unsigned short*)(Qf + (size_t)N_NODES * DIM);
    unsigned short* Vb = Kb + (size_t)N_NODES * DIM;
    unsigned short* Cb = Vb + (size_t)N_NODES * DIM;
    int* bucket_col = (int*)(Cb + (size_t)N_NODES * DIM);
    int* counts  = bucket_col + NE;
    int* offsets = counts + N_NODES;
    int* bsums   = offsets + N_NODES + 1;
    float* wsum  = (float*)(bsums + 256);
    float* S     = wsum + N_NODES;

    float* out_x = out;
    float* out_c = out + (size_t)N_NODES * DIM;

    // CSR build (row-bucketed column list)
    hipMemsetAsync(counts, 0, (size_t)N_NODES * sizeof(int), stream);
    k_hist <<<(NE + 255) / 256, 256, 0, stream>>>(eidx, counts);
    k_scan1<<<NSCAN_BLOCKS, 256, 0, stream>>>(counts, offsets, bsums);
    k_scan2<<<1, 256, 0, stream>>>(bsums);
    k_scan3<<<NSCAN_BLOCKS, 256, 0, stream>>>(offsets, counts, bsums);
    k_fill <<<(NE + 255) / 256, 256, 0, stream>>>(eidx, counts, bucket_col);

    // node projections + bf16 packing (persistent blocks)
    k_qkv<<<QKV_BLOCKS, 256, 0, stream>>>(
        x, coord, Wq, bq, Wk, bk, Wv, bv, Qf, Kb, Vb, Cb);

    // fused edge pass (quarter-per-edge), acc -> d_out, Σp -> wsum
    k_edge_fused<<<(N_NODES * 64 + 255) / 256, 256, 0, stream>>>(
        bucket_col, offsets, Qf, Kb, Vb, Cb, coord, Wc, bc,
        out_x, out_c, wsum);

    // deterministic global sum, then normalize + residual
    k_redsum<<<1, 1024, 0, stream>>>(wsum, S);
    k_finalize<<<2048, 256, 0, stream>>>(x, coord, S, out);
}

// Round 8
// 221.511 us; speedup vs baseline: 2.8967x; 1.0375x over previous
//
#include <hip/hip_runtime.h>
#include <math.h>

#define N_NODES 50000
#define DIM 64
#define NE 800000
#define NSCAN_BLOCKS ((N_NODES + 255) / 256)   // 196

static __device__ __forceinline__ float bf2f(unsigned short u) {
    return __uint_as_float(((unsigned int)u) << 16);
}
static __device__ __forceinline__ unsigned short f2bf(float f) {
    unsigned int u = __float_as_uint(f);
    u += 0x7fffu + ((u >> 16) & 1u);           // round-to-nearest-even
    return (unsigned short)(u >> 16);
}

// ---------------------------------------------------------------------------
// ws layout:
//   Qf      : N*DIM floats            (f32: wave-uniform read)
//   Kb,Vb,Cb: N*DIM ushorts each      (bf16: randomly gathered -> 1 line/row)
//   bucket_col : NE ints              (CSR position -> col node)
//   counts  : N ints (doubles as fill cursor)
//   offsets : N+1 ints
//   bsums   : 256 ints
//   wsum    : N floats
//   S       : 1 float
// ---------------------------------------------------------------------------

// QKV projections: 32 nodes/block, bf16 weights in LDS (32KB total ->
// 5 blocks/CU), 8 accumulating nodes per thread.
__global__ __launch_bounds__(256, 5) void k_qkv(
    const float* __restrict__ x, const float* __restrict__ coord,
    const float* __restrict__ Wq, const float* __restrict__ bq,
    const float* __restrict__ Wk, const float* __restrict__ bk,
    const float* __restrict__ Wv, const float* __restrict__ bv,
    float* __restrict__ Qf, unsigned short* __restrict__ Kb,
    unsigned short* __restrict__ Vb, unsigned short* __restrict__ Cb)
{
    __shared__ ushort4 WT2[3][1024];  // 24 KB: WT2[m][j2*64+d] = bf16 W[d][4j2..]
    __shared__ float4  xs4[32][16];   // 8 KB

    const int tid  = threadIdx.x;
    const int base = blockIdx.x * 32;

    // Stage weights (bf16). Dest index t consecutive per lane -> conflict-free.
    for (int t = tid; t < 1024; t += 256) {
        int d = t & 63, j2 = t >> 6;
        float4 a = ((const float4*)Wq)[d * 16 + j2];
        float4 b = ((const float4*)Wk)[d * 16 + j2];
        float4 c = ((const float4*)Wv)[d * 16 + j2];
        WT2[0][t] = make_ushort4(f2bf(a.x), f2bf(a.y), f2bf(a.z), f2bf(a.w));
        WT2[1][t] = make_ushort4(f2bf(b.x), f2bf(b.y), f2bf(b.z), f2bf(b.w));
        WT2[2][t] = make_ushort4(f2bf(c.x), f2bf(c.y), f2bf(c.z), f2bf(c.w));
    }
    // coord -> bf16 for this tile (coalesced)
    for (int t = tid; t < 32 * DIM; t += 256) {
        if (base + (t >> 6) < N_NODES)
            Cb[(size_t)base * DIM + t] = f2bf(coord[(size_t)base * DIM + t]);
    }
    // stage 32 node rows of x as float4
    for (int t = tid; t < 512; t += 256) {
        int r = t >> 4, j2 = t & 15;
        if (base + r < N_NODES)
            xs4[r][j2] = ((const float4*)x)[(size_t)(base + r) * 16 + j2];
    }
    __syncthreads();

    const int wv = tid >> 6;   // wave handles nodes wv*8 .. wv*8+7
    const int d  = tid & 63;
    const float bqv = bq[d], bkv = bk[d], bvv = bv[d];

    float aq[8], ak[8], av[8];
    #pragma unroll
    for (int r = 0; r < 8; ++r) { aq[r] = bqv; ak[r] = bkv; av[r] = bvv; }

    #pragma unroll 4
    for (int j2 = 0; j2 < 16; ++j2) {
        ushort4 uq = WT2[0][j2 * 64 + d];
        ushort4 uk = WT2[1][j2 * 64 + d];
        ushort4 uv = WT2[2][j2 * 64 + d];
        float wqx = bf2f(uq.x), wqy = bf2f(uq.y), wqz = bf2f(uq.z), wqw = bf2f(uq.w);
        float wkx = bf2f(uk.x), wky = bf2f(uk.y), wkz = bf2f(uk.z), wkw = bf2f(uk.w);
        float wvx = bf2f(uv.x), wvy = bf2f(uv.y), wvz = bf2f(uv.z), wvw = bf2f(uv.w);
        #pragma unroll
        for (int r = 0; r < 8; ++r) {
            float4 xv = xs4[wv * 8 + r][j2];   // wave-uniform broadcast
            aq[r] += xv.x * wqx + xv.y * wqy + xv.z * wqz + xv.w * wqw;
            ak[r] += xv.x * wkx + xv.y * wky + xv.z * wkz + xv.w * wkw;
            av[r] += xv.x * wvx + xv.y * wvy + xv.z * wvz + xv.w * wvw;
        }
    }
    #pragma unroll
    for (int r = 0; r < 8; ++r) {
        int n = base + wv * 8 + r;
        if (n < N_NODES) {
            Qf[(size_t)n * DIM + d] = aq[r];
            Kb[(size_t)n * DIM + d] = f2bf(ak[r]);
            Vb[(size_t)n * DIM + d] = f2bf(av[r]);
        }
    }
}

__global__ __launch_bounds__(256) void k_hist(
    const int* __restrict__ eidx, int* __restrict__ counts)
{
    int e = blockIdx.x * 256 + threadIdx.x;
    if (e < NE) atomicAdd(counts + eidx[e], 1);
}

__global__ __launch_bounds__(256) void k_scan1(
    const int* __restrict__ counts, int* __restrict__ offsets,
    int* __restrict__ bsums)
{
    __shared__ int tmp[256];
    int i = blockIdx.x * 256 + threadIdx.x;
    int v = (i < N_NODES) ? counts[i] : 0;
    tmp[threadIdx.x] = v;
    __syncthreads();
    #pragma unroll
    for (int off = 1; off < 256; off <<= 1) {
        int t = (threadIdx.x >= off) ? tmp[threadIdx.x - off] : 0;
        __syncthreads();
        tmp[threadIdx.x] += t;
        __syncthreads();
    }
    if (i < N_NODES) offsets[i] = tmp[threadIdx.x] - v;   // exclusive
    if (threadIdx.x == 255) bsums[blockIdx.x] = tmp[255];
}

__global__ __launch_bounds__(256) void k_scan2(int* __restrict__ bsums)
{
    __shared__ int tmp[256];
    int i = threadIdx.x;
    int v = (i < NSCAN_BLOCKS) ? bsums[i] : 0;
    tmp[i] = v;
    __syncthreads();
    #pragma unroll
    for (int off = 1; off < 256; off <<= 1) {
        int t = (i >= off) ? tmp[i - off] : 0;
        __syncthreads();
        tmp[i] += t;
        __syncthreads();
    }
    if (i < NSCAN_BLOCKS) bsums[i] = tmp[i] - v;
}

__global__ __launch_bounds__(256) void k_scan3(
    int* __restrict__ offsets, int* __restrict__ counts,
    const int* __restrict__ bsums)
{
    int i = blockIdx.x * 256 + threadIdx.x;
    if (i < N_NODES) {
        int o = offsets[i] + bsums[i >> 8];
        offsets[i] = o;
        counts[i]  = o;     // cursor for fill
    }
    if (i == 0) offsets[N_NODES] = NE;
}

__global__ __launch_bounds__(256) void k_fill(
    const int* __restrict__ eidx, int* __restrict__ cursor,
    int* __restrict__ bucket_col)
{
    int e = blockIdx.x * 256 + threadIdx.x;
    if (e < NE) {
        int pos = atomicAdd(cursor + eidx[e], 1);
        bucket_col[pos] = eidx[NE + e];
    }
}

// Fused edge pass: wave per node, 16-lane quarter per edge, lane = 4 dims.
// 2x unrolled (8 edges in flight). logit -> exp -> unnormalized accumulate.
__global__ __launch_bounds__(256) void k_edge_fused(
    const int* __restrict__ bucket_col, const int* __restrict__ offsets,
    const float* __restrict__ Qf, const unsigned short* __restrict__ Kb,
    const unsigned short* __restrict__ Vb, const unsigned short* __restrict__ Cb,
    const float* __restrict__ coord,
    const float* __restrict__ Wc, const float* __restrict__ bc,
    float* __restrict__ out_x, float* __restrict__ out_c,
    float* __restrict__ wsum)
{
    const int lane = threadIdx.x & 63;
    const int n = (blockIdx.x * 256 + threadIdx.x) >> 6;
    if (n >= N_NODES) return;
    const int qt = lane >> 4;          // quarter: which edge of the group of 4
    const int sl = lane & 15;          // dim-quad slot (dims 4sl..4sl+3)

    const float4 q4  = ((const float4*)Qf)[(size_t)n * 16 + sl];
    const float4 cr4 = ((const float4*)coord)[(size_t)n * 16 + sl];
    const float4 wc4 = ((const float4*)Wc)[sl];
    const float4 bc4 = ((const float4*)bc)[sl];

    const int s = offsets[n], t = offsets[n + 1];
    float4 accx = {0.f, 0.f, 0.f, 0.f};
    float4 accc = {0.f, 0.f, 0.f, 0.f};
    float psum = 0.0f;

    for (int base = s; base < t; base += 8) {
        int pos0 = base + qt;
        int pos1 = base + 4 + qt;
        bool valid0 = pos0 < t, valid1 = pos1 < t;
        int pc0 = valid0 ? pos0 : (t - 1);
        int pc1 = valid1 ? pos1 : (t - 1);
        int c0 = bucket_col[pc0];
        int c1 = bucket_col[pc1];
        size_t rb0 = (size_t)c0 * 16 + sl;
        size_t rb1 = (size_t)c1 * 16 + sl;
        ushort4 ku0 = ((const ushort4*)Kb)[rb0];
        ushort4 vu0 = ((const ushort4*)Vb)[rb0];
        ushort4 cu0 = ((const ushort4*)Cb)[rb0];
        ushort4 ku1 = ((const ushort4*)Kb)[rb1];
        ushort4 vu1 = ((const ushort4*)Vb)[rb1];
        ushort4 cu1 = ((const ushort4*)Cb)[rb1];

        // edge 0
        float d0 = q4.x * bf2f(ku0.x) + q4.y * bf2f(ku0.y)
                 + q4.z * bf2f(ku0.z) + q4.w * bf2f(ku0.w);
        float dx0x = cr4.x - bf2f(cu0.x), dx0y = cr4.y - bf2f(cu0.y);
        float dx0z = cr4.z - bf2f(cu0.z), dx0w = cr4.w - bf2f(cu0.w);
        float e0 = dx0x * dx0x + dx0y * dx0y + dx0z * dx0z + dx0w * dx0w;
        // edge 1
        float d1 = q4.x * bf2f(ku1.x) + q4.y * bf2f(ku1.y)
                 + q4.z * bf2f(ku1.z) + q4.w * bf2f(ku1.w);
        float dx1x = cr4.x - bf2f(cu1.x), dx1y = cr4.y - bf2f(cu1.y);
        float dx1z = cr4.z - bf2f(cu1.z), dx1w = cr4.w - bf2f(cu1.w);
        float e1 = dx1x * dx1x + dx1y * dx1y + dx1z * dx1z + dx1w * dx1w;

        #pragma unroll
        for (int off = 1; off <= 8; off <<= 1) {   // reduce within quarter
            d0 += __shfl_xor(d0, off);
            e0 += __shfl_xor(e0, off);
            d1 += __shfl_xor(d1, off);
            e1 += __shfl_xor(e1, off);
        }
        float p0 = valid0 ? __expf(d0) : 0.0f;
        float p1 = valid1 ? __expf(d1) : 0.0f;
        float dist0 = sqrtf(e0), dist1 = sqrtf(e1);
        psum += p0 + p1;
        accx.x += p0 * bf2f(vu0.x) + p1 * bf2f(vu1.x);
        accx.y += p0 * bf2f(vu0.y) + p1 * bf2f(vu1.y);
        accx.z += p0 * bf2f(vu0.z) + p1 * bf2f(vu1.z);
        accx.w += p0 * bf2f(vu0.w) + p1 * bf2f(vu1.w);
        accc.x += p0 * (dist0 * wc4.x + bc4.x) * dx0x
                + p1 * (dist1 * wc4.x + bc4.x) * dx1x;
        accc.y += p0 * (dist0 * wc4.y + bc4.y) * dx0y
                + p1 * (dist1 * wc4.y + bc4.y) * dx1y;
        accc.z += p0 * (dist0 * wc4.z + bc4.z) * dx0z
                + p1 * (dist1 * wc4.z + bc4.z) * dx1z;
        accc.w += p0 * (dist0 * wc4.w + bc4.w) * dx0w
                + p1 * (dist1 * wc4.w + bc4.w) * dx1w;
    }

    // cross-quarter combine (once per node)
    #pragma unroll
    for (int off = 16; off <= 32; off <<= 1) {
        accx.x += __shfl_xor(accx.x, off);
        accx.y += __shfl_xor(accx.y, off);
        accx.z += __shfl_xor(accx.z, off);
        accx.w += __shfl_xor(accx.w, off);
        accc.x += __shfl_xor(accc.x, off);
        accc.y += __shfl_xor(accc.y, off);
        accc.z += __shfl_xor(accc.z, off);
        accc.w += __shfl_xor(accc.w, off);
        psum   += __shfl_xor(psum, off);
    }
    if (lane < 16) {
        ((float4*)out_x)[(size_t)n * 16 + sl] = accx;   // unnormalized
        ((float4*)out_c)[(size_t)n * 16 + sl] = accc;
    }
    if (lane == 0) wsum[n] = psum;
}

// deterministic fixed-tree reduction of wsum -> S (single block)
__global__ __launch_bounds__(1024) void k_redsum(
    const float* __restrict__ wsum, float* __restrict__ S)
{
    __shared__ float red[16];
    float a = 0.0f;
    for (int i = threadIdx.x; i < N_NODES; i += 1024) a += wsum[i];
    #pragma unroll
    for (int off = 32; off; off >>= 1) a += __shfl_xor(a, off);
    if ((threadIdx.x & 63) == 0) red[threadIdx.x >> 6] = a;
    __syncthreads();
    if (threadIdx.x == 0) {
        float s = 0.0f;
        #pragma unroll
        for (int w = 0; w < 16; ++w) s += red[w];
        *S = s;
    }
}

// out = residual + out * (1/S), vectorized float4
__global__ __launch_bounds__(256) void k_finalize(
    const float* __restrict__ x, const float* __restrict__ coord,
    const float* __restrict__ S, float* __restrict__ out)
{
    const float inv = 1.0f / *S;
    const int nd4 = (N_NODES * DIM) / 4;      // 800000
    const float4* x4 = (const float4*)x;
    const float4* c4 = (const float4*)coord;
    float4* o4 = (float4*)out;
    for (int i = blockIdx.x * 256 + threadIdx.x; i < 2 * nd4;
         i += gridDim.x * 256) {
        float4 r = (i < nd4) ? x4[i] : c4[i - nd4];
        float4 a = o4[i];
        a.x = r.x + a.x * inv;
        a.y = r.y + a.y * inv;
        a.z = r.z + a.z * inv;
        a.w = r.w + a.w * inv;
        o4[i] = a;
    }
}

extern "C" void kernel_launch(void* const* d_in, const int* in_sizes, int n_in,
                              void* d_out, int out_size, void* d_ws, size_t ws_size,
                              hipStream_t stream)
{
    const float* x     = (const float*)d_in[0];
    const float* coord = (const float*)d_in[1];
    const float* Wq    = (const float*)d_in[2];
    const float* bq    = (const float*)d_in[3];
    const float* Wk    = (const float*)d_in[4];
    const float* bk    = (const float*)d_in[5];
    const float* Wv    = (const float*)d_in[6];
    const float* bv    = (const float*)d_in[7];
    const float* Wc    = (const float*)d_in[8];
    const float* bc    = (const float*)d_in[9];
    const int*   eidx  = (const int*)d_in[10];

    float* out = (float*)d_out;
    float* ws  = (float*)d_ws;

    float* Qf = ws;
    unsigned short* Kb = (unsigned short*)(Qf + (size_t)N_NODES * DIM);
    unsigned short* Vb = Kb + (size_t)N_NODES * DIM;
    unsigned short* Cb = Vb + (size_t)N_NODES * DIM;
    int* bucket_col = (int*)(Cb + (size_t)N_NODES * DIM);
    int* counts  = bucket_col + NE;
    int* offsets = counts + N_NODES;
    int* bsums   = offsets + N_NODES + 1;
    float* wsum  = (float*)(bsums + 256);
    float* S     = wsum + N_NODES;

    float* out_x = out;
    float* out_c = out + (size_t)N_NODES * DIM;

    // CSR build (row-bucketed column list)
    hipMemsetAsync(counts, 0, (size_t)N_NODES * sizeof(int), stream);
    k_hist <<<(NE + 255) / 256, 256, 0, stream>>>(eidx, counts);
    k_scan1<<<NSCAN_BLOCKS, 256, 0, stream>>>(counts, offsets, bsums);
    k_scan2<<<1, 256, 0, stream>>>(bsums);
    k_scan3<<<NSCAN_BLOCKS, 256, 0, stream>>>(offsets, counts, bsums);
    k_fill <<<(NE + 255) / 256, 256, 0, stream>>>(eidx, counts, bucket_col);

    // node projections + bf16 packing (32 nodes/block, 5 blocks/CU)
    k_qkv<<<(N_NODES + 31) / 32, 256, 0, stream>>>(
        x, coord, Wq, bq, Wk, bk, Wv, bv, Qf, Kb, Vb, Cb);

    // fused edge pass (quarter-per-edge, 2x unrolled), acc -> d_out
    k_edge_fused<<<(N_NODES * 64 + 255) / 256, 256, 0, stream>>>(
        bucket_col, offsets, Qf, Kb, Vb, Cb, coord, Wc, bc,
        out_x, out_c, wsum);

    // deterministic global sum, then normalize + residual
    k_redsum<<<1, 1024, 0, stream>>>(wsum, S);
    k_finalize<<<2048, 256, 0, stream>>>(x, coord, S, out);
}